// Round 1
// baseline (24.636 us; speedup 1.0000x reference)
//
#include <hip/hip_runtime.h>
#include <hip/hip_bf16.h>

// h[d,t] = sum_o R[d,o] * exp(glogp[d,o] * t),  glogp = -exp(p+gamma)
// D=2048, ORDER=64, L=2048. Output (1, D, L) float32.
//
// One wave (64 lanes) per d-row. Lane l computes t = l + 64k, k=0..31.
// Modes in groups of 8; per-mode geometric recurrence a *= lam^64.

#define DMODEL 2048
#define ORDER  64
#define SEQLEN 2048

__global__ __launch_bounds__(256) void imf_kernel(
    const float* __restrict__ gamma,
    const float* __restrict__ R,
    const float* __restrict__ p,
    float* __restrict__ out)
{
    const int wave = threadIdx.x >> 6;
    const int lane = threadIdx.x & 63;
    const int d = blockIdx.x * 4 + wave;

    const float LOG2E = 1.44269504088896340736f;

    float acc[32];
#pragma unroll
    for (int k = 0; k < 32; ++k) acc[k] = 0.0f;

    const float flane = (float)lane;

    for (int og = 0; og < 8; ++og) {
        float a[8], lam64[8];
#pragma unroll
        for (int j = 0; j < 8; ++j) {
            const int o = og * 8 + j;
            const float g  = gamma[d * ORDER + o];
            const float pp = p[d * ORDER + o];
            const float rr = R[d * ORDER + o];
            // glogp = -exp(p+gamma); gl2 = glogp * log2(e)
            const float gl2 = -__builtin_amdgcn_exp2f((pp + g) * LOG2E) * LOG2E;
            lam64[j] = __builtin_amdgcn_exp2f(gl2 * 64.0f);
            a[j] = __builtin_amdgcn_exp2f(gl2 * flane) * rr;  // R folded in
        }
#pragma unroll
        for (int k = 0; k < 32; ++k) {
            const float s = ((a[0] + a[1]) + (a[2] + a[3]))
                          + ((a[4] + a[5]) + (a[6] + a[7]));
            acc[k] += s;
#pragma unroll
            for (int j = 0; j < 8; ++j) a[j] *= lam64[j];
        }
    }

#pragma unroll
    for (int k = 0; k < 32; ++k) {
        out[d * SEQLEN + k * 64 + lane] = acc[k];
    }
}

extern "C" void kernel_launch(void* const* d_in, const int* in_sizes, int n_in,
                              void* d_out, int out_size, void* d_ws, size_t ws_size,
                              hipStream_t stream) {
    const float* gamma = (const float*)d_in[0];
    const float* R     = (const float*)d_in[1];
    const float* p     = (const float*)d_in[2];
    float* out = (float*)d_out;

    dim3 grid(DMODEL / 4);
    dim3 block(256);
    imf_kernel<<<grid, block, 0, stream>>>(gamma, R, p, out);
}

// Round 2
// 19.000 us; speedup vs baseline: 1.2967x; 1.2967x over previous
//
#include <hip/hip_runtime.h>

// h[d,t] = sum_o R[d,o] * exp(glogp[d,o] * t),  glogp = -exp(p+gamma)
// D=2048, ORDER=64, L=2048. Output (1, D, L) float32.
//
// One wave per d-row; lane l owns t = l + 64k, k=0..31.
// Mode constants (gl2, lam^64) computed wave-parallel (lane o = mode o),
// broadcast via shfl. Inner recurrence in packed fp32 (v_pk_*), modes
// paired into float2: 4 pk_mul + 4 pk_add per (og,k) step.

#define DMODEL 2048
#define ORDER  64
#define SEQLEN 2048

typedef __attribute__((ext_vector_type(2))) float f32x2;

__device__ __forceinline__ f32x2 pk_mul(f32x2 a, f32x2 b) {
    f32x2 d;
    asm("v_pk_mul_f32 %0, %1, %2" : "=v"(d) : "v"(a), "v"(b));
    return d;
}
__device__ __forceinline__ f32x2 pk_add(f32x2 a, f32x2 b) {
    f32x2 d;
    asm("v_pk_add_f32 %0, %1, %2" : "=v"(d) : "v"(a), "v"(b));
    return d;
}

__global__ __launch_bounds__(256) void imf_kernel(
    const float* __restrict__ gamma,
    const float* __restrict__ R,
    const float* __restrict__ p,
    float* __restrict__ out)
{
    const int wave = threadIdx.x >> 6;
    const int lane = threadIdx.x & 63;
    const int d = blockIdx.x * 4 + wave;

    const float LOG2E = 1.44269504088896340736f;

    // Stage 0: lane o computes the wave-uniform constants of mode o.
    // (coalesced loads; 2 exp2 for all 64 modes instead of 128)
    const float g_o  = gamma[d * ORDER + lane];
    const float p_o  = p[d * ORDER + lane];
    const float r_o  = R[d * ORDER + lane];
    const float gl2_o   = -__builtin_amdgcn_exp2f((p_o + g_o) * LOG2E) * LOG2E; // glogp*log2e
    const float lam64_o = __builtin_amdgcn_exp2f(gl2_o * 64.0f);                // lam^64

    const float tf = (float)lane;

    f32x2 accP[32];
#pragma unroll
    for (int k = 0; k < 32; ++k) accP[k] = (f32x2)(0.0f);

    for (int og = 0; og < 8; ++og) {
        f32x2 a2[4], lam2[4];
#pragma unroll
        for (int j = 0; j < 4; ++j) {
            const int o0 = og * 8 + 2 * j;
            const int o1 = o0 + 1;
            const float gl0 = __shfl(gl2_o, o0);
            const float gl1 = __shfl(gl2_o, o1);
            const float l0  = __shfl(lam64_o, o0);
            const float l1  = __shfl(lam64_o, o1);
            const float r0  = __shfl(r_o, o0);
            const float r1  = __shfl(r_o, o1);
            f32x2 a, l;
            a.x = __builtin_amdgcn_exp2f(gl0 * tf) * r0;   // per-lane init (t = lane)
            a.y = __builtin_amdgcn_exp2f(gl1 * tf) * r1;
            l.x = l0;
            l.y = l1;
            a2[j]  = a;
            lam2[j] = l;
        }
#pragma unroll
        for (int k = 0; k < 32; ++k) {
            // sum current state (t = lane + 64k), then advance by lam^64
            const f32x2 s = pk_add(pk_add(a2[0], a2[1]), pk_add(a2[2], a2[3]));
            accP[k] = pk_add(accP[k], s);
#pragma unroll
            for (int j = 0; j < 4; ++j) a2[j] = pk_mul(a2[j], lam2[j]);
        }
    }

#pragma unroll
    for (int k = 0; k < 32; ++k) {
        out[d * SEQLEN + k * 64 + lane] = accP[k].x + accP[k].y;
    }
}

extern "C" void kernel_launch(void* const* d_in, const int* in_sizes, int n_in,
                              void* d_out, int out_size, void* d_ws, size_t ws_size,
                              hipStream_t stream) {
    const float* gamma = (const float*)d_in[0];
    const float* R     = (const float*)d_in[1];
    const float* p     = (const float*)d_in[2];
    float* out = (float*)d_out;

    dim3 grid(DMODEL / 4);
    dim3 block(256);
    imf_kernel<<<grid, block, 0, stream>>>(gamma, R, p, out);
}